// Round 3
// baseline (895.561 us; speedup 1.0000x reference)
//
#include <hip/hip_runtime.h>

#define N_NODES 10000
#define N_EDGES 100000
#define IN_CH 64
#define EDGE_DIM 16
#define HID 128
#define HEADS 4
#define HC 512          // HEADS*HID
#define LAYERS 4
#define NUM_GRAPHS 256
#define NCAT 1152       // 512(xl) + 512(xr) + 128(res) packed cols
#define LDP 136         // padded LDS stride (bf16 elems)

typedef __bf16 bf16;
typedef __bf16 bf16x8 __attribute__((ext_vector_type(8)));
typedef __bf16 bf16x4 __attribute__((ext_vector_type(4)));
typedef float floatx4 __attribute__((ext_vector_type(4)));

__device__ __forceinline__ float elu_f(float x) { return x > 0.f ? x : (__expf(x) - 1.f); }

// ---------------- weight prep: WT[l][n][k] bf16 (pre-transposed, packed Wl|Wr|Wres)
__global__ __launch_bounds__(128) void k_prep_w(
    const float* __restrict__ Wl, const float* __restrict__ bl,
    const float* __restrict__ Wr, const float* __restrict__ br,
    const float* __restrict__ Wres, const float* __restrict__ bres,
    bf16* __restrict__ WT, float* __restrict__ bcat) {
    int bid = blockIdx.x;
    int i = bid / NCAT, n = bid % NCAT;
    int k = threadIdx.x;
    float w = 0.f, bias = 0.f;
    if (n < 512) {
        w = Wl[(size_t)i * HID * HC + (size_t)k * HC + n];
        bias = bl[i * HC + n];
    } else if (n < 1024) {
        int nn = n - 512;
        w = Wr[(size_t)i * HID * HC + (size_t)k * HC + nn];
        bias = br[i * HC + nn];
    } else if (i > 0) {
        int nn = n - 1024;
        w = Wres[(size_t)(i - 1) * HID * HID + (size_t)k * HID + nn];
        bias = bres[(i - 1) * HID + nn];
    }
    WT[(size_t)i * NCAT * HID + (size_t)n * HID + k] = (bf16)w;
    if (k == 0) bcat[i * NCAT + n] = bias;
}

// ---------------- h0 = elu(x @ Win + b_in) ----------------
__global__ __launch_bounds__(128) void k_init_h(const float* __restrict__ x,
                                                const float* __restrict__ Win,
                                                const float* __restrict__ b_in,
                                                bf16* __restrict__ h_bf) {
    __shared__ float xs[IN_CH];
    int n = blockIdx.x, t = threadIdx.x;
    if (t < IN_CH) xs[t] = x[(size_t)n * IN_CH + t];
    __syncthreads();
    float s = b_in[t];
#pragma unroll 8
    for (int k = 0; k < IN_CH; k++) s = fmaf(xs[k], Win[k * HID + t], s);
    h_bf[(size_t)n * HID + t] = (bf16)elu_f(s);
}

// ---------------- MFMA bf16 GEMM: C[M,NCAT] = A[M,128] @ WT^T + bias ------
__global__ __launch_bounds__(256, 2) void k_gemm_mfma(
    const bf16* __restrict__ A, const bf16* __restrict__ WT,
    const float* __restrict__ bcat, bf16* __restrict__ C, int M) {
    __shared__ __align__(16) unsigned short As[128 * LDP];
    __shared__ __align__(16) unsigned short Bs[128 * LDP];
    int t = threadIdx.x;
    int r0 = blockIdx.x * 128, c0 = blockIdx.y * 128;
#pragma unroll
    for (int i = 0; i < 8; i++) {
        int idx = t + i * 256;
        int row = idx >> 4;
        int ch = idx & 15;
        int r = r0 + row; if (r >= M) r = M - 1;
        uint4 va = *(const uint4*)(A + (size_t)r * HID + ch * 8);
        *(uint4*)&As[row * LDP + ch * 8] = va;
        uint4 vb = *(const uint4*)(WT + (size_t)(c0 + row) * HID + ch * 8);
        *(uint4*)&Bs[row * LDP + ch * 8] = vb;
    }
    __syncthreads();

    int wave = t >> 6, lane = t & 63;
    int wm = wave & 1, wn = wave >> 1;
    int quad = lane >> 4, lm = lane & 15;
    floatx4 zero = {0.f, 0.f, 0.f, 0.f};
    floatx4 acc[4][4];
#pragma unroll
    for (int mi = 0; mi < 4; mi++)
#pragma unroll
        for (int ni = 0; ni < 4; ni++) acc[mi][ni] = zero;

    const unsigned short* Ab = &As[(wm * 64 + lm) * LDP + quad * 8];
    const unsigned short* Bb = &Bs[(wn * 64 + lm) * LDP + quad * 8];
#pragma unroll
    for (int ks = 0; ks < 4; ks++) {
        bf16x8 af[4], bfr[4];
#pragma unroll
        for (int mi = 0; mi < 4; mi++) af[mi] = *(const bf16x8*)(Ab + mi * 16 * LDP + ks * 32);
#pragma unroll
        for (int ni = 0; ni < 4; ni++) bfr[ni] = *(const bf16x8*)(Bb + ni * 16 * LDP + ks * 32);
#pragma unroll
        for (int mi = 0; mi < 4; mi++)
#pragma unroll
            for (int ni = 0; ni < 4; ni++)
                acc[mi][ni] = __builtin_amdgcn_mfma_f32_16x16x32_bf16(af[mi], bfr[ni], acc[mi][ni], 0, 0, 0);
    }

#pragma unroll
    for (int ni = 0; ni < 4; ni++) {
        int col = c0 + wn * 64 + ni * 16 + lm;
        float bias = bcat[col];
#pragma unroll
        for (int mi = 0; mi < 4; mi++) {
#pragma unroll
            for (int r = 0; r < 4; r++) {
                int row = r0 + wm * 64 + mi * 16 + quad * 4 + r;
                if (row < M) C[(size_t)row * NCAT + col] = (bf16)(acc[mi][ni][r] + bias);
            }
        }
    }
}

// ---------------- CSR build (+ per-graph node counts folded in) ----------------
__global__ void k_degree(const int* __restrict__ ei, const int* __restrict__ batch,
                         int* __restrict__ deg, int* __restrict__ cnt) {
    int e = blockIdx.x * blockDim.x + threadIdx.x;
    if (e < N_EDGES) atomicAdd(&deg[ei[N_EDGES + e]], 1);
    if (e < N_NODES) atomicAdd(&cnt[batch[e]], 1);
}

__global__ __launch_bounds__(1024) void k_scan(const int* __restrict__ deg,
                                               int* __restrict__ row_start,
                                               int* __restrict__ cursor) {
    __shared__ int buf[1024];
    __shared__ int carry_s;
    int t = threadIdx.x;
    if (t == 0) { carry_s = 0; row_start[0] = 0; }
    __syncthreads();
    for (int base = 0; base < N_NODES; base += 1024) {
        int i = base + t;
        int v = (i < N_NODES) ? deg[i] : 0;
        buf[t] = v;
        __syncthreads();
        for (int off = 1; off < 1024; off <<= 1) {
            int add = (t >= off) ? buf[t - off] : 0;
            __syncthreads();
            buf[t] += add;
            __syncthreads();
        }
        int incl = buf[t];
        int carry = carry_s;
        if (i < N_NODES) {
            row_start[i + 1] = carry + incl;
            cursor[i] = carry + incl - v;
        }
        __syncthreads();
        if (t == 1023) carry_s = carry + buf[1023];
        __syncthreads();
    }
}

__global__ void k_scatter(const int* __restrict__ ei, int* __restrict__ cursor,
                          int* __restrict__ ssrc, int* __restrict__ sdst,
                          int* __restrict__ seid) {
    int e = blockIdx.x * blockDim.x + threadIdx.x;
    if (e < N_EDGES) {
        int d = ei[N_EDGES + e];
        int pos = atomicAdd(&cursor[d], 1);
        ssrc[pos] = ei[e];
        sdst[pos] = d;
        seid[pos] = e;
    }
}

// ---------------- edge-parallel logits: one 128-thread group per CSR slot ----
// slogit[j*4+h] = att[h] . leaky(xl[src] + xr[dst] + edge_attr@We)[h]
__global__ __launch_bounds__(256) void k_edge_logits(
    const bf16* __restrict__ xlr, const float* __restrict__ edge_attr,
    const int* __restrict__ ssrc, const int* __restrict__ sdst,
    const int* __restrict__ seid,
    const float* __restrict__ We_l, const float* __restrict__ att_l,
    float* __restrict__ slogit) {
    int j = blockIdx.x * 2 + (threadIdx.x >> 7);
    int t = threadIdx.x & 127;
    int c0 = (t >> 6) * 256 + (t & 63) * 4;
    int head = c0 >> 7;

    float4 we4[16];
#pragma unroll
    for (int k = 0; k < 16; k++) we4[k] = *(const float4*)(We_l + k * HC + c0);
    float4 att4 = *(const float4*)(att_l + head * HID + (c0 & 127));

    int s = ssrc[j], d = sdst[j], eid = seid[j];
    float ea[16];
    {
        const float4* eap = (const float4*)(edge_attr + (size_t)eid * EDGE_DIM);
        float4 a0 = eap[0], a1 = eap[1], a2 = eap[2], a3 = eap[3];
        ea[0]=a0.x; ea[1]=a0.y; ea[2]=a0.z; ea[3]=a0.w;
        ea[4]=a1.x; ea[5]=a1.y; ea[6]=a1.z; ea[7]=a1.w;
        ea[8]=a2.x; ea[9]=a2.y; ea[10]=a2.z; ea[11]=a2.w;
        ea[12]=a3.x; ea[13]=a3.y; ea[14]=a3.z; ea[15]=a3.w;
    }
    float xl0, xl1, xl2, xl3, xr0, xr1, xr2, xr3;
    {
        bf16x4 v = *(const bf16x4*)(xlr + (size_t)s * NCAT + c0);
        xl0 = (float)v[0]; xl1 = (float)v[1]; xl2 = (float)v[2]; xl3 = (float)v[3];
        bf16x4 w = *(const bf16x4*)(xlr + (size_t)d * NCAT + 512 + c0);
        xr0 = (float)w[0]; xr1 = (float)w[1]; xr2 = (float)w[2]; xr3 = (float)w[3];
    }
    float e4x = 0.f, e4y = 0.f, e4z = 0.f, e4w = 0.f;
#pragma unroll
    for (int k = 0; k < 16; k++) {
        e4x = fmaf(ea[k], we4[k].x, e4x);
        e4y = fmaf(ea[k], we4[k].y, e4y);
        e4z = fmaf(ea[k], we4[k].z, e4z);
        e4w = fmaf(ea[k], we4[k].w, e4w);
    }
    float mx = xl0 + xr0 + e4x; mx = mx > 0.f ? mx : 0.2f * mx;
    float my = xl1 + xr1 + e4y; my = my > 0.f ? my : 0.2f * my;
    float mz = xl2 + xr2 + e4z; mz = mz > 0.f ? mz : 0.2f * mz;
    float mw = xl3 + xr3 + e4w; mw = mw > 0.f ? mw : 0.2f * mw;
    float partial = mx * att4.x + my * att4.y + mz * att4.z + mw * att4.w;
#pragma unroll
    for (int off = 1; off < 32; off <<= 1) partial += __shfl_xor(partial, off, 64);
    if ((t & 31) == 0) slogit[(size_t)j * 4 + head] = partial;
}

// ---------------- node-parallel softmax + aggregate + head-mean + LN + ELU ----
__global__ __launch_bounds__(128) void k_edge_agg(
    const bf16* __restrict__ xlr,
    const int* __restrict__ row_start, const int* __restrict__ ssrc,
    const float* __restrict__ slogit,
    const float* __restrict__ bgat_l, const float* __restrict__ gamma_l,
    const float* __restrict__ beta_l,
    int has_res,
    const int* __restrict__ batch, float* __restrict__ hsum, int do_pool,
    bf16* __restrict__ hbf_out) {
    int n = blockIdx.x;
    int t = threadIdx.x;
    int wave = t >> 6;
    int lane = t & 63;
    int c0 = wave * 256 + lane * 4;
    int head = c0 >> 7;

    int e0 = row_start[n], e1 = row_start[n + 1];

    // pass 1: max logit for this head (broadcast 4B reads), 2 indep chains
    float m0 = -1e30f, m1 = -1e30f;
    int j = e0;
    for (; j + 1 < e1; j += 2) {
        m0 = fmaxf(m0, slogit[(size_t)j * 4 + head]);
        m1 = fmaxf(m1, slogit[(size_t)(j + 1) * 4 + head]);
    }
    if (j < e1) m0 = fmaxf(m0, slogit[(size_t)j * 4 + head]);
    float m = fmaxf(m0, m1);

    // pass 2: p = exp(lg - m), acc += p * xl[src], two independent streams
    float l0 = 0.f, l1 = 0.f;
    float4 a0 = {0.f, 0.f, 0.f, 0.f}, a1 = {0.f, 0.f, 0.f, 0.f};
    j = e0;
    for (; j + 1 < e1; j += 2) {
        int s0 = ssrc[j], s1 = ssrc[j + 1];
        float p0 = __expf(slogit[(size_t)j * 4 + head] - m);
        float p1 = __expf(slogit[(size_t)(j + 1) * 4 + head] - m);
        bf16x4 v0 = *(const bf16x4*)(xlr + (size_t)s0 * NCAT + c0);
        bf16x4 v1 = *(const bf16x4*)(xlr + (size_t)s1 * NCAT + c0);
        l0 += p0; l1 += p1;
        a0.x = fmaf(p0, (float)v0[0], a0.x); a0.y = fmaf(p0, (float)v0[1], a0.y);
        a0.z = fmaf(p0, (float)v0[2], a0.z); a0.w = fmaf(p0, (float)v0[3], a0.w);
        a1.x = fmaf(p1, (float)v1[0], a1.x); a1.y = fmaf(p1, (float)v1[1], a1.y);
        a1.z = fmaf(p1, (float)v1[2], a1.z); a1.w = fmaf(p1, (float)v1[3], a1.w);
    }
    if (j < e1) {
        int s0 = ssrc[j];
        float p0 = __expf(slogit[(size_t)j * 4 + head] - m);
        bf16x4 v0 = *(const bf16x4*)(xlr + (size_t)s0 * NCAT + c0);
        l0 += p0;
        a0.x = fmaf(p0, (float)v0[0], a0.x); a0.y = fmaf(p0, (float)v0[1], a0.y);
        a0.z = fmaf(p0, (float)v0[2], a0.z); a0.w = fmaf(p0, (float)v0[3], a0.w);
    }
    float inv = 1.f / (l0 + l1 + 1e-16f);

    __shared__ float sout[HC];
    __shared__ float red[4];
    sout[c0 + 0] = (a0.x + a1.x) * inv;
    sout[c0 + 1] = (a0.y + a1.y) * inv;
    sout[c0 + 2] = (a0.z + a1.z) * inv;
    sout[c0 + 3] = (a0.w + a1.w) * inv;
    __syncthreads();

    int c = t;
    float v = 0.25f * (sout[c] + sout[c + 128] + sout[c + 256] + sout[c + 384]) + bgat_l[c];
    float s1 = v, s2 = v * v;
#pragma unroll
    for (int off = 1; off < 64; off <<= 1) {
        s1 += __shfl_xor(s1, off, 64);
        s2 += __shfl_xor(s2, off, 64);
    }
    if (lane == 0) { red[wave * 2] = s1; red[wave * 2 + 1] = s2; }
    __syncthreads();
    s1 = red[0] + red[2];
    s2 = red[1] + red[3];
    float mu = s1 * (1.f / HID);
    float var = s2 * (1.f / HID) - mu * mu;
    float rstd = rsqrtf(var + 1e-5f);
    float y = fmaf(gamma_l[c] * (v - mu), rstd, beta_l[c]);
    y = elu_f(y);
    if (has_res) y += (float)xlr[(size_t)n * NCAT + 1024 + c];
    if (do_pool) atomicAdd(&hsum[(size_t)batch[n] * HID + c], y);
    else hbf_out[(size_t)n * HID + c] = (bf16)y;
}

// ---------------- MLP head ----------------
__global__ __launch_bounds__(128) void k_mlp(const float* __restrict__ hsum,
                                             const int* __restrict__ cnt,
                                             const float* __restrict__ W1, const float* __restrict__ b1,
                                             const float* __restrict__ W2, const float* __restrict__ b2,
                                             const float* __restrict__ W3, const float* __restrict__ b3,
                                             float* __restrict__ out) {
    int g = blockIdx.x, t = threadIdx.x;
    __shared__ float hg[HID], z1[HID], z2[64];
    float invc = 1.f / fmaxf((float)cnt[g], 1.f);
    hg[t] = hsum[(size_t)g * HID + t] * invc;
    __syncthreads();
    float s = b1[t];
#pragma unroll 8
    for (int k = 0; k < HID; k++) s = fmaf(hg[k], W1[k * HID + t], s);
    z1[t] = fmaxf(s, 0.f);
    __syncthreads();
    if (t < 64) {
        float s2 = b2[t];
#pragma unroll 8
        for (int k = 0; k < HID; k++) s2 = fmaf(z1[k], W2[k * 64 + t], s2);
        z2[t] = fmaxf(s2, 0.f);
    }
    __syncthreads();
    if (t < 64) {
        float s3 = z2[t] * W3[t];
#pragma unroll
        for (int off = 1; off < 64; off <<= 1) s3 += __shfl_xor(s3, off, 64);
        if (t == 0) out[g] = s3 + b3[0];
    }
}

// ---------------- host launcher ----------------
extern "C" void kernel_launch(void* const* d_in, const int* in_sizes, int n_in,
                              void* d_out, int out_size, void* d_ws, size_t ws_size,
                              hipStream_t stream) {
    const float* x         = (const float*)d_in[0];
    const int*   ei        = (const int*)  d_in[1];
    const float* edge_attr = (const float*)d_in[2];
    const int*   batch     = (const int*)  d_in[3];
    const float* Win       = (const float*)d_in[4];
    const float* b_in      = (const float*)d_in[5];
    const float* Wl        = (const float*)d_in[6];
    const float* bl        = (const float*)d_in[7];
    const float* Wr        = (const float*)d_in[8];
    const float* br        = (const float*)d_in[9];
    const float* We        = (const float*)d_in[10];
    const float* att       = (const float*)d_in[11];
    const float* b_gat     = (const float*)d_in[12];
    const float* gamma     = (const float*)d_in[13];
    const float* beta      = (const float*)d_in[14];
    const float* Wres      = (const float*)d_in[15];
    const float* bres      = (const float*)d_in[16];
    const float* W1        = (const float*)d_in[17];
    const float* b1        = (const float*)d_in[18];
    const float* W2        = (const float*)d_in[19];
    const float* b2        = (const float*)d_in[20];
    const float* W3        = (const float*)d_in[21];
    const float* b3        = (const float*)d_in[22];
    float* out = (float*)d_out;

    char* ws = (char*)d_ws;
    size_t off = 0;
    auto alloc = [&](size_t bytes) -> void* {
        void* p = ws + off;
        off = (off + bytes + 255) & ~(size_t)255;
        return p;
    };
    bf16*  h_bf    = (bf16*) alloc((size_t)N_NODES * HID * 2);
    bf16*  xlr     = (bf16*) alloc((size_t)N_NODES * NCAT * 2);
    bf16*  WT      = (bf16*) alloc((size_t)LAYERS * NCAT * HID * 2);
    float* bcat    = (float*)alloc((size_t)LAYERS * NCAT * 4);
    float* slogit  = (float*)alloc((size_t)N_EDGES * 4 * 4);
    // contiguous zero region: [hsum | cnt | deg]
    char*  zbase   = ws + off;
    float* hsum    = (float*)alloc((size_t)NUM_GRAPHS * HID * 4);
    int*   cnt     = (int*)  alloc((size_t)NUM_GRAPHS * 4);
    int*   deg     = (int*)  alloc((size_t)N_NODES * 4);
    size_t zlen    = (size_t)((ws + off) - zbase);
    int*   rowst   = (int*)  alloc((size_t)(N_NODES + 1) * 4);
    int*   cursor  = (int*)  alloc((size_t)N_NODES * 4);
    int*   ssrc    = (int*)  alloc((size_t)N_EDGES * 4);
    int*   sdst    = (int*)  alloc((size_t)N_EDGES * 4);
    int*   seid    = (int*)  alloc((size_t)N_EDGES * 4);
    (void)ws_size; // requires ~30 MB

    hipMemsetAsync(zbase, 0, zlen, stream);

    k_prep_w<<<LAYERS * NCAT, 128, 0, stream>>>(Wl, bl, Wr, br, Wres, bres, WT, bcat);
    k_degree<<<(N_EDGES + 255) / 256, 256, 0, stream>>>(ei, batch, deg, cnt);
    k_scan<<<1, 1024, 0, stream>>>(deg, rowst, cursor);
    k_scatter<<<(N_EDGES + 255) / 256, 256, 0, stream>>>(ei, cursor, ssrc, sdst, seid);
    k_init_h<<<N_NODES, 128, 0, stream>>>(x, Win, b_in, h_bf);

    const int MG = (N_NODES + 127) / 128;  // 79
    for (int i = 0; i < LAYERS; i++) {
        int ntiles = (i > 0) ? (NCAT / 128) : (1024 / 128);
        k_gemm_mfma<<<dim3(MG, ntiles), 256, 0, stream>>>(
            h_bf, WT + (size_t)i * NCAT * HID, bcat + (size_t)i * NCAT, xlr, N_NODES);
        k_edge_logits<<<N_EDGES / 2, 256, 0, stream>>>(
            xlr, edge_attr, ssrc, sdst, seid,
            We + (size_t)i * EDGE_DIM * HC, att + (size_t)i * HEADS * HID, slogit);
        k_edge_agg<<<N_NODES, 128, 0, stream>>>(
            xlr, rowst, ssrc, slogit,
            b_gat + (size_t)i * HID, gamma + (size_t)i * HID, beta + (size_t)i * HID,
            (i > 0) ? 1 : 0,
            batch, hsum, (i == LAYERS - 1) ? 1 : 0, h_bf);
    }

    k_mlp<<<NUM_GRAPHS, 128, 0, stream>>>(hsum, cnt, W1, b1, W2, b2, W3, b3, out);
}

// Round 4
// 512.961 us; speedup vs baseline: 1.7459x; 1.7459x over previous
//
#include <hip/hip_runtime.h>

#define N_NODES 10000
#define N_EDGES 100000
#define IN_CH 64
#define EDGE_DIM 16
#define HID 128
#define HEADS 4
#define HC 512          // HEADS*HID
#define LAYERS 4
#define NUM_GRAPHS 256
#define NCAT 1152       // 512(xl) + 512(xr) + 128(res) packed cols
#define LDP 136         // padded LDS stride (bf16 elems)
#define EPB 32          // edges per block in logits kernel

typedef __bf16 bf16;
typedef __bf16 bf16x8 __attribute__((ext_vector_type(8)));
typedef __bf16 bf16x4 __attribute__((ext_vector_type(4)));
typedef float floatx4 __attribute__((ext_vector_type(4)));

__device__ __forceinline__ float elu_f(float x) { return x > 0.f ? x : (__expf(x) - 1.f); }

// ---------------- weight prep: WT[l][n][k] bf16, coalesced via LDS transpose ----
// grid (9, LAYERS), block 128. tile nt: 0-3=Wl, 4-7=Wr, 8=Wres.
__global__ __launch_bounds__(128) void k_prep_w(
    const float* __restrict__ Wl, const float* __restrict__ bl,
    const float* __restrict__ Wr, const float* __restrict__ br,
    const float* __restrict__ Wres, const float* __restrict__ bres,
    bf16* __restrict__ WT, float* __restrict__ bcat) {
    __shared__ float tile[128][129];
    int nt = blockIdx.x, i = blockIdx.y;
    int t = threadIdx.x;
    int n0 = nt * 128;
    const float* base = nullptr; const float* bsrc = nullptr; int ld = 0;
    if (nt < 4)       { base = Wl + (size_t)i * HID * HC + n0;            bsrc = bl + i * HC + n0;              ld = HC; }
    else if (nt < 8)  { base = Wr + (size_t)i * HID * HC + (n0 - 512);    bsrc = br + i * HC + (n0 - 512);      ld = HC; }
    else if (i > 0)   { base = Wres + (size_t)(i - 1) * HID * HID;        bsrc = bres + (size_t)(i - 1) * HID;  ld = HID; }
    if (base) {
        for (int r = 0; r < 128; r++) tile[r][t] = base[(size_t)r * ld + t];
    } else {
        for (int r = 0; r < 128; r++) tile[r][t] = 0.f;
    }
    __syncthreads();
    int n = n0 + t;
    bcat[(size_t)i * NCAT + n] = base ? bsrc[t] : 0.f;
    bf16* dst = WT + ((size_t)i * NCAT + n) * HID;
#pragma unroll
    for (int kc = 0; kc < 16; kc++) {
        bf16x8 v;
#pragma unroll
        for (int u = 0; u < 8; u++) v[u] = (bf16)tile[kc * 8 + u][t];
        *(bf16x8*)(dst + kc * 8) = v;
    }
}

// ---------------- h0 = elu(x @ Win + b_in) ----------------
__global__ __launch_bounds__(128) void k_init_h(const float* __restrict__ x,
                                                const float* __restrict__ Win,
                                                const float* __restrict__ b_in,
                                                bf16* __restrict__ h_bf) {
    __shared__ float xs[IN_CH];
    int n = blockIdx.x, t = threadIdx.x;
    if (t < IN_CH) xs[t] = x[(size_t)n * IN_CH + t];
    __syncthreads();
    float s = b_in[t];
#pragma unroll 8
    for (int k = 0; k < IN_CH; k++) s = fmaf(xs[k], Win[k * HID + t], s);
    h_bf[(size_t)n * HID + t] = (bf16)elu_f(s);
}

// ---------------- MFMA bf16 GEMM: C[M,NCAT] = A[M,128] @ WT^T + bias ------
__global__ __launch_bounds__(256, 2) void k_gemm_mfma(
    const bf16* __restrict__ A, const bf16* __restrict__ WT,
    const float* __restrict__ bcat, bf16* __restrict__ C, int M) {
    __shared__ __align__(16) unsigned short As[128 * LDP];
    __shared__ __align__(16) unsigned short Bs[128 * LDP];
    int t = threadIdx.x;
    int r0 = blockIdx.x * 128, c0 = blockIdx.y * 128;
#pragma unroll
    for (int i = 0; i < 8; i++) {
        int idx = t + i * 256;
        int row = idx >> 4;
        int ch = idx & 15;
        int r = r0 + row; if (r >= M) r = M - 1;
        uint4 va = *(const uint4*)(A + (size_t)r * HID + ch * 8);
        *(uint4*)&As[row * LDP + ch * 8] = va;
        uint4 vb = *(const uint4*)(WT + (size_t)(c0 + row) * HID + ch * 8);
        *(uint4*)&Bs[row * LDP + ch * 8] = vb;
    }
    __syncthreads();

    int wave = t >> 6, lane = t & 63;
    int wm = wave & 1, wn = wave >> 1;
    int quad = lane >> 4, lm = lane & 15;
    floatx4 zero = {0.f, 0.f, 0.f, 0.f};
    floatx4 acc[4][4];
#pragma unroll
    for (int mi = 0; mi < 4; mi++)
#pragma unroll
        for (int ni = 0; ni < 4; ni++) acc[mi][ni] = zero;

    const unsigned short* Ab = &As[(wm * 64 + lm) * LDP + quad * 8];
    const unsigned short* Bb = &Bs[(wn * 64 + lm) * LDP + quad * 8];
#pragma unroll
    for (int ks = 0; ks < 4; ks++) {
        bf16x8 af[4], bfr[4];
#pragma unroll
        for (int mi = 0; mi < 4; mi++) af[mi] = *(const bf16x8*)(Ab + mi * 16 * LDP + ks * 32);
#pragma unroll
        for (int ni = 0; ni < 4; ni++) bfr[ni] = *(const bf16x8*)(Bb + ni * 16 * LDP + ks * 32);
#pragma unroll
        for (int mi = 0; mi < 4; mi++)
#pragma unroll
            for (int ni = 0; ni < 4; ni++)
                acc[mi][ni] = __builtin_amdgcn_mfma_f32_16x16x32_bf16(af[mi], bfr[ni], acc[mi][ni], 0, 0, 0);
    }

#pragma unroll
    for (int ni = 0; ni < 4; ni++) {
        int col = c0 + wn * 64 + ni * 16 + lm;
        float bias = bcat[col];
#pragma unroll
        for (int mi = 0; mi < 4; mi++) {
#pragma unroll
            for (int r = 0; r < 4; r++) {
                int row = r0 + wm * 64 + mi * 16 + quad * 4 + r;
                if (row < M) C[(size_t)row * NCAT + col] = (bf16)(acc[mi][ni][r] + bias);
            }
        }
    }
}

// ---------------- CSR build (+ per-graph node counts folded in) ----------------
__global__ void k_degree(const int* __restrict__ ei, const int* __restrict__ batch,
                         int* __restrict__ deg, int* __restrict__ cnt) {
    int e = blockIdx.x * blockDim.x + threadIdx.x;
    if (e < N_EDGES) atomicAdd(&deg[ei[N_EDGES + e]], 1);
    if (e < N_NODES) atomicAdd(&cnt[batch[e]], 1);
}

// shfl-based scan: 3 barriers per 1024-chunk instead of 20
__global__ __launch_bounds__(1024) void k_scan(const int* __restrict__ deg,
                                               int* __restrict__ row_start,
                                               int* __restrict__ cursor) {
    __shared__ int wsum[16];
    __shared__ int carry_s;
    int t = threadIdx.x;
    int wave = t >> 6, lane = t & 63;
    if (t == 0) { carry_s = 0; row_start[0] = 0; }
    __syncthreads();
    for (int base = 0; base < N_NODES; base += 1024) {
        int i = base + t;
        int v = (i < N_NODES) ? deg[i] : 0;
        int incl = v;
#pragma unroll
        for (int off = 1; off < 64; off <<= 1) {
            int u = __shfl_up(incl, off, 64);
            if (lane >= off) incl += u;
        }
        if (lane == 63) wsum[wave] = incl;
        __syncthreads();
        if (wave == 0) {
            int ws = (lane < 16) ? wsum[lane] : 0;
#pragma unroll
            for (int off = 1; off < 16; off <<= 1) {
                int u = __shfl_up(ws, off, 64);
                if (lane >= off) ws += u;
            }
            if (lane < 16) wsum[lane] = ws;
        }
        __syncthreads();
        int carry = carry_s;
        int chunk_total = wsum[15];
        int total = carry + ((wave == 0) ? 0 : wsum[wave - 1]) + incl;
        if (i < N_NODES) { row_start[i + 1] = total; cursor[i] = total - v; }
        __syncthreads();
        if (t == 0) carry_s = carry + chunk_total;
        // next chunk's first barrier orders this write before reads
    }
}

// scatter edges into CSR order; also permute edge_attr so logits reads are coalesced
__global__ void k_scatter(const int* __restrict__ ei, const float* __restrict__ edge_attr,
                          int* __restrict__ cursor,
                          int* __restrict__ ssrc, int* __restrict__ sdst,
                          float* __restrict__ ea_s) {
    int e = blockIdx.x * blockDim.x + threadIdx.x;
    if (e < N_EDGES) {
        int d = ei[N_EDGES + e];
        int pos = atomicAdd(&cursor[d], 1);
        ssrc[pos] = ei[e];
        sdst[pos] = d;
        const float4* s4 = (const float4*)(edge_attr + (size_t)e * EDGE_DIM);
        float4* d4 = (float4*)(ea_s + (size_t)pos * EDGE_DIM);
        d4[0] = s4[0]; d4[1] = s4[1]; d4[2] = s4[2]; d4[3] = s4[3];
    }
}

// ---------------- edge-parallel logits, strip of EPB edges per 128-thr block ----
// We held in 64 VGPRs across the strip (launch_bounds(...,1) -> no remat pressure).
__global__ __launch_bounds__(128, 1) void k_edge_logits(
    const bf16* __restrict__ xlr, const float* __restrict__ ea_s,
    const int* __restrict__ ssrc, const int* __restrict__ sdst,
    const float* __restrict__ We_l, const float* __restrict__ att_l,
    float* __restrict__ slogit) {
    int j0 = blockIdx.x * EPB;
    int t = threadIdx.x;
    int c0 = (t >> 6) * 256 + (t & 63) * 4;
    int head = c0 >> 7;

    __shared__ float eas[EPB][16];
    __shared__ int s_sh[EPB], d_sh[EPB];
    {
        const float4* src = (const float4*)(ea_s + (size_t)j0 * EDGE_DIM);
        ((float4*)&eas[0][0])[t] = src[t];          // 128 float4 = whole strip
        if (t < EPB) s_sh[t] = ssrc[j0 + t];
        else if (t < 2 * EPB) d_sh[t - EPB] = sdst[j0 + t - EPB];
    }
    float4 we4[16];
#pragma unroll
    for (int k = 0; k < 16; k++) we4[k] = *(const float4*)(We_l + k * HC + c0);
    float4 att4 = *(const float4*)(att_l + head * HID + (c0 & 127));
    __syncthreads();

    for (int jj = 0; jj < EPB; jj++) {
        int s = s_sh[jj], d = d_sh[jj];
        bf16x4 vl = *(const bf16x4*)(xlr + (size_t)s * NCAT + c0);
        bf16x4 vr = *(const bf16x4*)(xlr + (size_t)d * NCAT + 512 + c0);
        float e4x = 0.f, e4y = 0.f, e4z = 0.f, e4w = 0.f;
#pragma unroll
        for (int k = 0; k < 16; k++) {
            float ea = eas[jj][k];
            e4x = fmaf(ea, we4[k].x, e4x);
            e4y = fmaf(ea, we4[k].y, e4y);
            e4z = fmaf(ea, we4[k].z, e4z);
            e4w = fmaf(ea, we4[k].w, e4w);
        }
        float mx = (float)vl[0] + (float)vr[0] + e4x; mx = mx > 0.f ? mx : 0.2f * mx;
        float my = (float)vl[1] + (float)vr[1] + e4y; my = my > 0.f ? my : 0.2f * my;
        float mz = (float)vl[2] + (float)vr[2] + e4z; mz = mz > 0.f ? mz : 0.2f * mz;
        float mw = (float)vl[3] + (float)vr[3] + e4w; mw = mw > 0.f ? mw : 0.2f * mw;
        float partial = mx * att4.x + my * att4.y + mz * att4.z + mw * att4.w;
#pragma unroll
        for (int off = 1; off < 32; off <<= 1) partial += __shfl_xor(partial, off, 64);
        if (((t & 63) & 31) == 0) slogit[(size_t)(j0 + jj) * 4 + head] = partial;
    }
}

// ---------------- node-parallel softmax + aggregate + head-mean + LN + ELU ----
// single pass: softmax shift-invariance lets us skip the max pass (|logit| ~ O(8)).
__global__ __launch_bounds__(128) void k_edge_agg(
    const bf16* __restrict__ xlr,
    const int* __restrict__ row_start, const int* __restrict__ ssrc,
    const float* __restrict__ slogit,
    const float* __restrict__ bgat_l, const float* __restrict__ gamma_l,
    const float* __restrict__ beta_l,
    int has_res,
    const int* __restrict__ batch, float* __restrict__ hsum, int do_pool,
    bf16* __restrict__ hbf_out) {
    int n = blockIdx.x;
    int t = threadIdx.x;
    int wave = t >> 6;
    int lane = t & 63;
    int c0 = wave * 256 + lane * 4;
    int head = c0 >> 7;

    int e0 = row_start[n], e1 = row_start[n + 1];

    float l0 = 0.f, l1 = 0.f;
    float4 a0 = {0.f, 0.f, 0.f, 0.f}, a1 = {0.f, 0.f, 0.f, 0.f};
    int j = e0;
    for (; j + 1 < e1; j += 2) {
        int s0 = ssrc[j], s1 = ssrc[j + 1];
        float p0 = __expf(slogit[(size_t)j * 4 + head]);
        float p1 = __expf(slogit[(size_t)(j + 1) * 4 + head]);
        bf16x4 v0 = *(const bf16x4*)(xlr + (size_t)s0 * NCAT + c0);
        bf16x4 v1 = *(const bf16x4*)(xlr + (size_t)s1 * NCAT + c0);
        l0 += p0; l1 += p1;
        a0.x = fmaf(p0, (float)v0[0], a0.x); a0.y = fmaf(p0, (float)v0[1], a0.y);
        a0.z = fmaf(p0, (float)v0[2], a0.z); a0.w = fmaf(p0, (float)v0[3], a0.w);
        a1.x = fmaf(p1, (float)v1[0], a1.x); a1.y = fmaf(p1, (float)v1[1], a1.y);
        a1.z = fmaf(p1, (float)v1[2], a1.z); a1.w = fmaf(p1, (float)v1[3], a1.w);
    }
    if (j < e1) {
        int s0 = ssrc[j];
        float p0 = __expf(slogit[(size_t)j * 4 + head]);
        bf16x4 v0 = *(const bf16x4*)(xlr + (size_t)s0 * NCAT + c0);
        l0 += p0;
        a0.x = fmaf(p0, (float)v0[0], a0.x); a0.y = fmaf(p0, (float)v0[1], a0.y);
        a0.z = fmaf(p0, (float)v0[2], a0.z); a0.w = fmaf(p0, (float)v0[3], a0.w);
    }
    float inv = 1.f / (l0 + l1 + 1e-16f);

    __shared__ float sout[HC];
    __shared__ float red[4];
    sout[c0 + 0] = (a0.x + a1.x) * inv;
    sout[c0 + 1] = (a0.y + a1.y) * inv;
    sout[c0 + 2] = (a0.z + a1.z) * inv;
    sout[c0 + 3] = (a0.w + a1.w) * inv;
    __syncthreads();

    int c = t;
    float v = 0.25f * (sout[c] + sout[c + 128] + sout[c + 256] + sout[c + 384]) + bgat_l[c];
    float s1 = v, s2 = v * v;
#pragma unroll
    for (int off = 1; off < 64; off <<= 1) {
        s1 += __shfl_xor(s1, off, 64);
        s2 += __shfl_xor(s2, off, 64);
    }
    if (lane == 0) { red[wave * 2] = s1; red[wave * 2 + 1] = s2; }
    __syncthreads();
    s1 = red[0] + red[2];
    s2 = red[1] + red[3];
    float mu = s1 * (1.f / HID);
    float var = s2 * (1.f / HID) - mu * mu;
    float rstd = rsqrtf(var + 1e-5f);
    float y = fmaf(gamma_l[c] * (v - mu), rstd, beta_l[c]);
    y = elu_f(y);
    if (has_res) y += (float)xlr[(size_t)n * NCAT + 1024 + c];
    if (do_pool) atomicAdd(&hsum[(size_t)batch[n] * HID + c], y);
    else hbf_out[(size_t)n * HID + c] = (bf16)y;
}

// ---------------- MLP head ----------------
__global__ __launch_bounds__(128) void k_mlp(const float* __restrict__ hsum,
                                             const int* __restrict__ cnt,
                                             const float* __restrict__ W1, const float* __restrict__ b1,
                                             const float* __restrict__ W2, const float* __restrict__ b2,
                                             const float* __restrict__ W3, const float* __restrict__ b3,
                                             float* __restrict__ out) {
    int g = blockIdx.x, t = threadIdx.x;
    __shared__ float hg[HID], z1[HID], z2[64];
    float invc = 1.f / fmaxf((float)cnt[g], 1.f);
    hg[t] = hsum[(size_t)g * HID + t] * invc;
    __syncthreads();
    float s = b1[t];
#pragma unroll 8
    for (int k = 0; k < HID; k++) s = fmaf(hg[k], W1[k * HID + t], s);
    z1[t] = fmaxf(s, 0.f);
    __syncthreads();
    if (t < 64) {
        float s2 = b2[t];
#pragma unroll 8
        for (int k = 0; k < HID; k++) s2 = fmaf(z1[k], W2[k * 64 + t], s2);
        z2[t] = fmaxf(s2, 0.f);
    }
    __syncthreads();
    if (t < 64) {
        float s3 = z2[t] * W3[t];
#pragma unroll
        for (int off = 1; off < 64; off <<= 1) s3 += __shfl_xor(s3, off, 64);
        if (t == 0) out[g] = s3 + b3[0];
    }
}

// ---------------- host launcher ----------------
extern "C" void kernel_launch(void* const* d_in, const int* in_sizes, int n_in,
                              void* d_out, int out_size, void* d_ws, size_t ws_size,
                              hipStream_t stream) {
    const float* x         = (const float*)d_in[0];
    const int*   ei        = (const int*)  d_in[1];
    const float* edge_attr = (const float*)d_in[2];
    const int*   batch     = (const int*)  d_in[3];
    const float* Win       = (const float*)d_in[4];
    const float* b_in      = (const float*)d_in[5];
    const float* Wl        = (const float*)d_in[6];
    const float* bl        = (const float*)d_in[7];
    const float* Wr        = (const float*)d_in[8];
    const float* br        = (const float*)d_in[9];
    const float* We        = (const float*)d_in[10];
    const float* att       = (const float*)d_in[11];
    const float* b_gat     = (const float*)d_in[12];
    const float* gamma     = (const float*)d_in[13];
    const float* beta      = (const float*)d_in[14];
    const float* Wres      = (const float*)d_in[15];
    const float* bres      = (const float*)d_in[16];
    const float* W1        = (const float*)d_in[17];
    const float* b1        = (const float*)d_in[18];
    const float* W2        = (const float*)d_in[19];
    const float* b2        = (const float*)d_in[20];
    const float* W3        = (const float*)d_in[21];
    const float* b3        = (const float*)d_in[22];
    float* out = (float*)d_out;

    char* ws = (char*)d_ws;
    size_t off = 0;
    auto alloc = [&](size_t bytes) -> void* {
        void* p = ws + off;
        off = (off + bytes + 255) & ~(size_t)255;
        return p;
    };
    bf16*  h_bf    = (bf16*) alloc((size_t)N_NODES * HID * 2);
    bf16*  xlr     = (bf16*) alloc((size_t)N_NODES * NCAT * 2);
    bf16*  WT      = (bf16*) alloc((size_t)LAYERS * NCAT * HID * 2);
    float* bcat    = (float*)alloc((size_t)LAYERS * NCAT * 4);
    float* slogit  = (float*)alloc((size_t)N_EDGES * 4 * 4);
    float* ea_s    = (float*)alloc((size_t)N_EDGES * EDGE_DIM * 4);
    // contiguous zero region: [hsum | cnt | deg]
    char*  zbase   = ws + off;
    float* hsum    = (float*)alloc((size_t)NUM_GRAPHS * HID * 4);
    int*   cnt     = (int*)  alloc((size_t)NUM_GRAPHS * 4);
    int*   deg     = (int*)  alloc((size_t)N_NODES * 4);
    size_t zlen    = (size_t)((ws + off) - zbase);
    int*   rowst   = (int*)  alloc((size_t)(N_NODES + 1) * 4);
    int*   cursor  = (int*)  alloc((size_t)N_NODES * 4);
    int*   ssrc    = (int*)  alloc((size_t)N_EDGES * 4);
    int*   sdst    = (int*)  alloc((size_t)N_EDGES * 4);
    (void)ws_size; // requires ~37 MB

    hipMemsetAsync(zbase, 0, zlen, stream);

    k_prep_w<<<dim3(9, LAYERS), 128, 0, stream>>>(Wl, bl, Wr, br, Wres, bres, WT, bcat);
    k_degree<<<(N_EDGES + 255) / 256, 256, 0, stream>>>(ei, batch, deg, cnt);
    k_scan<<<1, 1024, 0, stream>>>(deg, rowst, cursor);
    k_scatter<<<(N_EDGES + 255) / 256, 256, 0, stream>>>(ei, edge_attr, cursor, ssrc, sdst, ea_s);
    k_init_h<<<N_NODES, 128, 0, stream>>>(x, Win, b_in, h_bf);

    const int MG = (N_NODES + 127) / 128;  // 79
    for (int i = 0; i < LAYERS; i++) {
        int ntiles = (i > 0) ? (NCAT / 128) : (1024 / 128);
        k_gemm_mfma<<<dim3(MG, ntiles), 256, 0, stream>>>(
            h_bf, WT + (size_t)i * NCAT * HID, bcat + (size_t)i * NCAT, xlr, N_NODES);
        k_edge_logits<<<N_EDGES / EPB, 128, 0, stream>>>(
            xlr, ea_s, ssrc, sdst,
            We + (size_t)i * EDGE_DIM * HC, att + (size_t)i * HEADS * HID, slogit);
        k_edge_agg<<<N_NODES, 128, 0, stream>>>(
            xlr, rowst, ssrc, slogit,
            b_gat + (size_t)i * HID, gamma + (size_t)i * HID, beta + (size_t)i * HID,
            (i > 0) ? 1 : 0,
            batch, hsum, (i == LAYERS - 1) ? 1 : 0, h_bf);
    }

    k_mlp<<<NUM_GRAPHS, 128, 0, stream>>>(hsum, cnt, W1, b1, W2, b2, W3, b3, out);
}